// Round 1
// baseline (916.977 us; speedup 1.0000x reference)
//
#include <hip/hip_runtime.h>
#include <math.h>

// Problem constants (from reference)
constexpr int NN = 50000;
constexpr int EE = 800000;
constexpr int INC = 256, CC1 = 128, CC2 = 64;

// ---------------- small helper kernels ----------------

__global__ void init_kernel(float* __restrict__ deg, float* __restrict__ sums, int n) {
    int i = blockIdx.x * 256 + threadIdx.x;
    if (i < 1024) sums[i] = 0.0f;           // BN sums + params area
    if (i < n) deg[i] = 1.0f;               // self-loop weight
}

__global__ void deg_kernel(const int* __restrict__ col, const float* __restrict__ ew,
                           float* __restrict__ deg, int e_cnt) {
    int e = blockIdx.x * 256 + threadIdx.x;
    if (e < e_cnt) atomicAdd(&deg[col[e]], ew[e]);
}

__global__ void dinv_kernel(float* __restrict__ deg, int n) {
    int i = blockIdx.x * 256 + threadIdx.x;
    if (i < n) deg[i] = rsqrtf(deg[i]);     // deg >= 1 always (self loop)
}

__global__ void norm_kernel(const int* __restrict__ row, const int* __restrict__ col,
                            const float* __restrict__ ew, const float* __restrict__ dinv,
                            float* __restrict__ nrm, int e_cnt) {
    int e = blockIdx.x * 256 + threadIdx.x;
    if (e < e_cnt) nrm[e] = dinv[row[e]] * ew[e] * dinv[col[e]];
}

// ---------------- GEMM: C[n,m] = sum_k A[n,k] B[k,m] ----------------
// Block: 256 threads, 16 rows of A staged in LDS; W row loads coalesced.
template<int K, int M>
__global__ void gemm_kernel(const float* __restrict__ A, const float* __restrict__ B,
                            float* __restrict__ C, int n) {
    constexpr int ROWS = 16;
    __shared__ float xs[ROWS][K];
    const int tid = threadIdx.x;
    const int block_row = blockIdx.x * ROWS;
    for (int i = tid; i < ROWS * K; i += 256) {
        int r = i / K, k = i % K;
        int nn = block_row + r;
        xs[r][k] = (nn < n) ? A[(long long)nn * K + k] : 0.0f;
    }
    __syncthreads();
    constexpr int RG = 256 / M;      // row groups per pass (2 for M=128, 4 for M=64)
    constexpr int RPT = ROWS / RG;   // rows per thread
    const int m = tid % M;
    const int r0 = tid / M;
    float acc[RPT];
#pragma unroll
    for (int i = 0; i < RPT; i++) acc[i] = 0.0f;
#pragma unroll 4
    for (int k = 0; k < K; k++) {
        float w = B[k * M + m];
#pragma unroll
        for (int i = 0; i < RPT; i++) acc[i] += xs[r0 + i * RG][k] * w;
    }
#pragma unroll
    for (int i = 0; i < RPT; i++) {
        int nn = block_row + r0 + i * RG;
        if (nn < n) C[(long long)nn * M + m] = acc[i];
    }
}

// ---------------- aggregation ----------------

// out[i,c] = h[i,c] * dinv[i]^2 + b[c]   (self-loop term + bias; also zero-init)
template<int C>
__global__ void init_agg_kernel(const float* __restrict__ h, const float* __restrict__ dinv,
                                const float* __restrict__ b, float* __restrict__ out, int n) {
    int idx = blockIdx.x * 256 + threadIdx.x;
    if (idx >= n * C) return;
    int nn = idx / C, c = idx % C;
    float d = dinv[nn];
    out[idx] = h[idx] * d * d + b[c];
}

// edge-parallel scatter: thread = (edge, channel)
template<int C>
__global__ void scatter_kernel(const float* __restrict__ h, const int* __restrict__ row,
                               const int* __restrict__ col, const float* __restrict__ nrm,
                               float* __restrict__ out, int e_cnt) {
    int idx = blockIdx.x * 256 + threadIdx.x;
    if (idx >= e_cnt * C) return;
    int e = idx / C;
    int c = idx % C;
    float v = h[(long long)row[e] * C + c] * nrm[e];
    atomicAdd(&out[(long long)col[e] * C + c], v);
}

// ---------------- batchnorm ----------------

// column sums: each block covers 128 rows, partial per-thread then LDS reduce, 2 atomics/ch
template<int C>
__global__ void bnstats_kernel(const float* __restrict__ x, float* __restrict__ sum,
                               float* __restrict__ sumsq, int n) {
    constexpr int RG = 256 / C;
    constexpr int ROWS = 128;
    const int c = threadIdx.x % C;
    const int rg = threadIdx.x / C;
    const int base = blockIdx.x * ROWS;
    float s = 0.0f, ss = 0.0f;
    for (int r = rg; r < ROWS; r += RG) {
        int nn = base + r;
        if (nn < n) {
            float v = x[(long long)nn * C + c];
            s += v; ss += v * v;
        }
    }
    __shared__ float ls[256], lss[256];
    ls[threadIdx.x] = s; lss[threadIdx.x] = ss;
    __syncthreads();
    if (rg == 0) {
#pragma unroll
        for (int g = 1; g < RG; g++) { s += ls[g * C + c]; ss += lss[g * C + c]; }
        atomicAdd(&sum[c], s);
        atomicAdd(&sumsq[c], ss);
    }
}

// scale/shift from sums; extra_bias folds skip-path bias into shift (may be null)
__global__ void bnparams_kernel(const float* __restrict__ sum, const float* __restrict__ sumsq,
                                const float* __restrict__ gamma, const float* __restrict__ beta,
                                const float* __restrict__ extra_bias,
                                float* __restrict__ scale, float* __restrict__ shift,
                                int n, int c_cnt) {
    int c = threadIdx.x;
    if (c < c_cnt) {
        float inv_n = 1.0f / (float)n;
        float mu = sum[c] * inv_n;
        float var = sumsq[c] * inv_n - mu * mu;
        if (var < 0.0f) var = 0.0f;
        float sc = gamma[c] * rsqrtf(var + 1e-5f);
        float sh = beta[c] - mu * sc;
        if (extra_bias) sh += extra_bias[c];
        scale[c] = sc; shift[c] = sh;
    }
}

// x1 = gelu(bn(agg1)), exact erf form
template<int C>
__global__ void bn_gelu_kernel(const float* __restrict__ x, const float* __restrict__ scale,
                               const float* __restrict__ shift, float* __restrict__ out, int total) {
    int i = blockIdx.x * 256 + threadIdx.x;
    if (i >= total) return;
    int c = i % C;
    float v = x[i] * scale[c] + shift[c];
    out[i] = v * 0.5f * (1.0f + erff(v * 0.70710678f));
}

// out = bn(agg2) + skip   (bs already folded into shift)
template<int C>
__global__ void final_kernel(const float* __restrict__ x, const float* __restrict__ scale,
                             const float* __restrict__ shift, const float* __restrict__ skip,
                             float* __restrict__ out, int total) {
    int i = blockIdx.x * 256 + threadIdx.x;
    if (i >= total) return;
    int c = i % C;
    out[i] = x[i] * scale[c] + shift[c] + skip[i];
}

// ---------------- launch ----------------

extern "C" void kernel_launch(void* const* d_in, const int* in_sizes, int n_in,
                              void* d_out, int out_size, void* d_ws, size_t ws_size,
                              hipStream_t stream) {
    const float* x   = (const float*)d_in[0];
    const int*   ei  = (const int*)d_in[1];
    const float* ew  = (const float*)d_in[2];
    const float* W1  = (const float*)d_in[3];
    const float* b1  = (const float*)d_in[4];
    const float* W2  = (const float*)d_in[5];
    const float* b2  = (const float*)d_in[6];
    const float* g1  = (const float*)d_in[7];
    const float* be1 = (const float*)d_in[8];
    const float* g2  = (const float*)d_in[9];
    const float* be2 = (const float*)d_in[10];
    const float* Ws  = (const float*)d_in[11];
    const float* bs  = (const float*)d_in[12];
    float* out = (float*)d_out;

    const int* row = ei;            // edge_index[0]
    const int* col = ei + EE;       // edge_index[1]

    // workspace layout (floats)
    float* w = (float*)d_ws;
    float* dinv  = w;                          // N
    float* nrm   = dinv + NN;                  // E
    float* stats = nrm + EE;                   // 1024: sums/params
    float* sum1   = stats;        // 128
    float* sumsq1 = stats + 128;  // 128
    float* sum2   = stats + 256;  // 64
    float* sumsq2 = stats + 320;  // 64
    float* scale1 = stats + 384;  // 128
    float* shift1 = stats + 512;  // 128
    float* scale2 = stats + 640;  // 64
    float* shift2 = stats + 704;  // 64
    float* h1    = stats + 1024;               // N*128
    float* agg1  = h1 + (long long)NN * CC1;   // N*128
    float* h2    = agg1 + (long long)NN * CC1; // N*64
    float* agg2  = h2 + (long long)NN * CC2;   // N*64
    float* skip  = agg2 + (long long)NN * CC2; // N*64

    const int nb_N   = (NN + 255) / 256;
    const int nb_E   = (EE + 255) / 256;

    // degree / norm precompute
    init_kernel<<<nb_N, 256, 0, stream>>>(dinv, stats, NN);
    deg_kernel<<<nb_E, 256, 0, stream>>>(col, ew, dinv, EE);
    dinv_kernel<<<nb_N, 256, 0, stream>>>(dinv, NN);
    norm_kernel<<<nb_E, 256, 0, stream>>>(row, col, ew, dinv, nrm, EE);

    // skip = x @ Ws  (bs folded into BN2 shift)
    gemm_kernel<INC, CC2><<<(NN + 15) / 16, 256, 0, stream>>>(x, Ws, skip, NN);

    // conv1: h1 = x @ W1; agg with self loops + b1
    gemm_kernel<INC, CC1><<<(NN + 15) / 16, 256, 0, stream>>>(x, W1, h1, NN);
    init_agg_kernel<CC1><<<(NN * CC1 + 255) / 256, 256, 0, stream>>>(h1, dinv, b1, agg1, NN);
    scatter_kernel<CC1><<<(EE * CC1 + 255) / 256, 256, 0, stream>>>(h1, row, col, nrm, agg1, EE);

    // BN1 + GELU -> x1 (reuse h1 buffer)
    bnstats_kernel<CC1><<<(NN + 127) / 128, 256, 0, stream>>>(agg1, sum1, sumsq1, NN);
    bnparams_kernel<<<1, 128, 0, stream>>>(sum1, sumsq1, g1, be1, nullptr, scale1, shift1, NN, CC1);
    bn_gelu_kernel<CC1><<<(NN * CC1 + 255) / 256, 256, 0, stream>>>(agg1, scale1, shift1, h1, NN * CC1);

    // conv2: h2 = x1 @ W2; agg with self loops + b2
    gemm_kernel<CC1, CC2><<<(NN + 15) / 16, 256, 0, stream>>>(h1, W2, h2, NN);
    init_agg_kernel<CC2><<<(NN * CC2 + 255) / 256, 256, 0, stream>>>(h2, dinv, b2, agg2, NN);
    scatter_kernel<CC2><<<(EE * CC2 + 255) / 256, 256, 0, stream>>>(h2, row, col, nrm, agg2, EE);

    // BN2 (+bs) + skip -> out
    bnstats_kernel<CC2><<<(NN + 127) / 128, 256, 0, stream>>>(agg2, sum2, sumsq2, NN);
    bnparams_kernel<<<1, 64, 0, stream>>>(sum2, sumsq2, g2, be2, bs, scale2, shift2, NN, CC2);
    final_kernel<CC2><<<(NN * CC2 + 255) / 256, 256, 0, stream>>>(agg2, scale2, shift2, skip, out, NN * CC2);

    (void)in_sizes; (void)n_in; (void)out_size; (void)ws_size;
}

// Round 2
// 563.238 us; speedup vs baseline: 1.6280x; 1.6280x over previous
//
#include <hip/hip_runtime.h>
#include <math.h>

// Problem constants (from reference)
constexpr int NN = 50000;
constexpr int EE = 800000;
constexpr int INC = 256, CC1 = 128, CC2 = 64;

// ---------------- precompute kernels ----------------

// zero BN stats area + cursor, deg=1 (self loop), count=0
__global__ void init_kernel(float* __restrict__ deg, int* __restrict__ count,
                            float* __restrict__ stats, int* __restrict__ cursor, int n) {
    int i = blockIdx.x * 256 + threadIdx.x;
    if (i < 1024) stats[i] = 0.0f;
    if (i == 0) *cursor = 0;
    if (i < n) { deg[i] = 1.0f; count[i] = 0; }
}

// weighted degree at targets + incoming-edge counts
__global__ void deg_count_kernel(const int* __restrict__ col, const float* __restrict__ ew,
                                 float* __restrict__ deg, int* __restrict__ count, int e_cnt) {
    int e = blockIdx.x * 256 + threadIdx.x;
    if (e < e_cnt) {
        int c = col[e];
        atomicAdd(&deg[c], ew[e]);
        atomicAdd(&count[c], 1);
    }
}

__global__ void dinv_kernel(float* __restrict__ deg, int n) {
    int i = blockIdx.x * 256 + threadIdx.x;
    if (i < n) deg[i] = rsqrtf(deg[i]);     // deg >= 1 always (self loop)
}

// allocate CSR segment per node (order irrelevant -> no prefix sum needed)
__global__ void alloc_kernel(const int* __restrict__ count, int* __restrict__ start,
                             int* __restrict__ cur, int* __restrict__ cursor, int n) {
    int i = blockIdx.x * 256 + threadIdx.x;
    if (i < n) {
        int s = atomicAdd(cursor, count[i]);
        start[i] = s;
        cur[i] = s;
    }
}

// fill CSR: source row + fused normalized edge weight, grouped by destination
__global__ void fill_kernel(const int* __restrict__ row, const int* __restrict__ col,
                            const float* __restrict__ ew, const float* __restrict__ dinv,
                            int* __restrict__ cur, int* __restrict__ csr_row,
                            float* __restrict__ csr_nrm, int e_cnt) {
    int e = blockIdx.x * 256 + threadIdx.x;
    if (e < e_cnt) {
        int r = row[e], c = col[e];
        float nv = dinv[r] * ew[e] * dinv[c];
        int pos = atomicAdd(&cur[c], 1);
        csr_row[pos] = r;
        csr_nrm[pos] = nv;
    }
}

// ---------------- GEMM: C[n,m] = sum_k A[n,k] B[k,m] ----------------
template<int K, int M>
__global__ void gemm_kernel(const float* __restrict__ A, const float* __restrict__ B,
                            float* __restrict__ C, int n) {
    constexpr int ROWS = 16;
    __shared__ float xs[ROWS][K];
    const int tid = threadIdx.x;
    const int block_row = blockIdx.x * ROWS;
    for (int i = tid; i < ROWS * K; i += 256) {
        int r = i / K, k = i % K;
        int nn = block_row + r;
        xs[r][k] = (nn < n) ? A[(long long)nn * K + k] : 0.0f;
    }
    __syncthreads();
    constexpr int RG = 256 / M;
    constexpr int RPT = ROWS / RG;
    const int m = tid % M;
    const int r0 = tid / M;
    float acc[RPT];
#pragma unroll
    for (int i = 0; i < RPT; i++) acc[i] = 0.0f;
#pragma unroll 4
    for (int k = 0; k < K; k++) {
        float w = B[k * M + m];
#pragma unroll
        for (int i = 0; i < RPT; i++) acc[i] += xs[r0 + i * RG][k] * w;
    }
#pragma unroll
    for (int i = 0; i < RPT; i++) {
        int nn = block_row + r0 + i * RG;
        if (nn < n) C[(long long)nn * M + m] = acc[i];
    }
}

// ---------------- gather aggregation (no atomics) ----------------
// out[i] = h[i]*dinv[i]^2 + b + sum_{j in csr seg of i} h[csr_row[j]] * csr_nrm[j]
// TPN = C/4 threads per node, each holding a float4 of channels.
template<int C>
__global__ void gather_agg_kernel(const float* __restrict__ h, const float* __restrict__ dinv,
                                  const float* __restrict__ b, const int* __restrict__ csr_row,
                                  const float* __restrict__ csr_nrm, const int* __restrict__ start,
                                  const int* __restrict__ count, float* __restrict__ out, int n) {
    constexpr int TPN = C / 4;
    int gid = blockIdx.x * 256 + threadIdx.x;
    int node = gid / TPN;
    int part = gid % TPN;
    if (node >= n) return;
    int c4 = part * 4;
    float d = dinv[node];
    const float4* hv = (const float4*)(h + (long long)node * C + c4);
    float4 bb = *(const float4*)(b + c4);
    float4 hh = *hv;
    float4 acc;
    float d2 = d * d;
    acc.x = hh.x * d2 + bb.x;
    acc.y = hh.y * d2 + bb.y;
    acc.z = hh.z * d2 + bb.z;
    acc.w = hh.w * d2 + bb.w;
    int s = start[node];
    int e = s + count[node];
    for (int j = s; j < e; j++) {
        int nbr = csr_row[j];        // broadcast across the TPN group
        float w = csr_nrm[j];
        float4 v = *(const float4*)(h + (long long)nbr * C + c4);
        acc.x += v.x * w;
        acc.y += v.y * w;
        acc.z += v.z * w;
        acc.w += v.w * w;
    }
    *(float4*)(out + (long long)node * C + c4) = acc;
}

// ---------------- batchnorm ----------------

template<int C>
__global__ void bnstats_kernel(const float* __restrict__ x, float* __restrict__ sum,
                               float* __restrict__ sumsq, int n) {
    constexpr int RG = 256 / C;
    constexpr int ROWS = 128;
    const int c = threadIdx.x % C;
    const int rg = threadIdx.x / C;
    const int base = blockIdx.x * ROWS;
    float s = 0.0f, ss = 0.0f;
    for (int r = rg; r < ROWS; r += RG) {
        int nn = base + r;
        if (nn < n) {
            float v = x[(long long)nn * C + c];
            s += v; ss += v * v;
        }
    }
    __shared__ float ls[256], lss[256];
    ls[threadIdx.x] = s; lss[threadIdx.x] = ss;
    __syncthreads();
    if (rg == 0) {
#pragma unroll
        for (int g = 1; g < RG; g++) { s += ls[g * C + c]; ss += lss[g * C + c]; }
        atomicAdd(&sum[c], s);
        atomicAdd(&sumsq[c], ss);
    }
}

__global__ void bnparams_kernel(const float* __restrict__ sum, const float* __restrict__ sumsq,
                                const float* __restrict__ gamma, const float* __restrict__ beta,
                                const float* __restrict__ extra_bias,
                                float* __restrict__ scale, float* __restrict__ shift,
                                int n, int c_cnt) {
    int c = threadIdx.x;
    if (c < c_cnt) {
        float inv_n = 1.0f / (float)n;
        float mu = sum[c] * inv_n;
        float var = sumsq[c] * inv_n - mu * mu;
        if (var < 0.0f) var = 0.0f;
        float sc = gamma[c] * rsqrtf(var + 1e-5f);
        float sh = beta[c] - mu * sc;
        if (extra_bias) sh += extra_bias[c];
        scale[c] = sc; shift[c] = sh;
    }
}

template<int C>
__global__ void bn_gelu_kernel(const float* __restrict__ x, const float* __restrict__ scale,
                               const float* __restrict__ shift, float* __restrict__ out, int total) {
    int i = blockIdx.x * 256 + threadIdx.x;
    if (i >= total) return;
    int c = i % C;
    float v = x[i] * scale[c] + shift[c];
    out[i] = v * 0.5f * (1.0f + erff(v * 0.70710678f));
}

template<int C>
__global__ void final_kernel(const float* __restrict__ x, const float* __restrict__ scale,
                             const float* __restrict__ shift, const float* __restrict__ skip,
                             float* __restrict__ out, int total) {
    int i = blockIdx.x * 256 + threadIdx.x;
    if (i >= total) return;
    int c = i % C;
    out[i] = x[i] * scale[c] + shift[c] + skip[i];
}

// ---------------- launch ----------------

extern "C" void kernel_launch(void* const* d_in, const int* in_sizes, int n_in,
                              void* d_out, int out_size, void* d_ws, size_t ws_size,
                              hipStream_t stream) {
    const float* x   = (const float*)d_in[0];
    const int*   ei  = (const int*)d_in[1];
    const float* ew  = (const float*)d_in[2];
    const float* W1  = (const float*)d_in[3];
    const float* b1  = (const float*)d_in[4];
    const float* W2  = (const float*)d_in[5];
    const float* b2  = (const float*)d_in[6];
    const float* g1  = (const float*)d_in[7];
    const float* be1 = (const float*)d_in[8];
    const float* g2  = (const float*)d_in[9];
    const float* be2 = (const float*)d_in[10];
    const float* Ws  = (const float*)d_in[11];
    const float* bs  = (const float*)d_in[12];
    float* out = (float*)d_out;

    const int* row = ei;            // edge_index[0]
    const int* col = ei + EE;       // edge_index[1]

    // workspace layout (floats; all segments multiple-of-4 for float4 alignment)
    float* w = (float*)d_ws;
    float* dinv   = w;                            // N
    int*   count  = (int*)(dinv + NN);            // N
    int*   startp = count + NN;                   // N
    int*   curp   = startp + NN;                  // N
    int*   csr_row = curp + NN;                   // E
    float* csr_nrm = (float*)(csr_row + EE);      // E
    float* stats  = csr_nrm + EE;                 // 1024
    int*   cursor = (int*)(stats + 1020);         // last slot of stats area
    float* sum1   = stats;        // 128
    float* sumsq1 = stats + 128;  // 128
    float* sum2   = stats + 256;  // 64
    float* sumsq2 = stats + 320;  // 64
    float* scale1 = stats + 384;  // 128
    float* shift1 = stats + 512;  // 128
    float* scale2 = stats + 640;  // 64
    float* shift2 = stats + 704;  // 64
    float* h1    = stats + 1024;                  // N*128
    float* agg1  = h1 + (long long)NN * CC1;      // N*128
    float* h2    = agg1 + (long long)NN * CC1;    // N*64
    float* agg2  = h2 + (long long)NN * CC2;      // N*64
    float* skip  = agg2 + (long long)NN * CC2;    // N*64

    const int nb_N = (NN + 255) / 256;
    const int nb_E = (EE + 255) / 256;

    // CSR + norm precompute
    init_kernel<<<nb_N, 256, 0, stream>>>(dinv, count, stats, cursor, NN);
    deg_count_kernel<<<nb_E, 256, 0, stream>>>(col, ew, dinv, count, EE);
    dinv_kernel<<<nb_N, 256, 0, stream>>>(dinv, NN);
    alloc_kernel<<<nb_N, 256, 0, stream>>>(count, startp, curp, cursor, NN);
    fill_kernel<<<nb_E, 256, 0, stream>>>(row, col, ew, dinv, curp, csr_row, csr_nrm, EE);

    // skip = x @ Ws  (bs folded into BN2 shift)
    gemm_kernel<INC, CC2><<<(NN + 15) / 16, 256, 0, stream>>>(x, Ws, skip, NN);

    // conv1: h1 = x @ W1; gather-aggregate (self loop + b1 fused)
    gemm_kernel<INC, CC1><<<(NN + 15) / 16, 256, 0, stream>>>(x, W1, h1, NN);
    gather_agg_kernel<CC1><<<(NN * (CC1 / 4) + 255) / 256, 256, 0, stream>>>(
        h1, dinv, b1, csr_row, csr_nrm, startp, count, agg1, NN);

    // BN1 + GELU -> x1 (reuse h1 buffer)
    bnstats_kernel<CC1><<<(NN + 127) / 128, 256, 0, stream>>>(agg1, sum1, sumsq1, NN);
    bnparams_kernel<<<1, 128, 0, stream>>>(sum1, sumsq1, g1, be1, nullptr, scale1, shift1, NN, CC1);
    bn_gelu_kernel<CC1><<<(NN * CC1 + 255) / 256, 256, 0, stream>>>(agg1, scale1, shift1, h1, NN * CC1);

    // conv2: h2 = x1 @ W2; gather-aggregate (self loop + b2 fused)
    gemm_kernel<CC1, CC2><<<(NN + 15) / 16, 256, 0, stream>>>(h1, W2, h2, NN);
    gather_agg_kernel<CC2><<<(NN * (CC2 / 4) + 255) / 256, 256, 0, stream>>>(
        h2, dinv, b2, csr_row, csr_nrm, startp, count, agg2, NN);

    // BN2 (+bs) + skip -> out
    bnstats_kernel<CC2><<<(NN + 127) / 128, 256, 0, stream>>>(agg2, sum2, sumsq2, NN);
    bnparams_kernel<<<1, 64, 0, stream>>>(sum2, sumsq2, g2, be2, bs, scale2, shift2, NN, CC2);
    final_kernel<CC2><<<(NN * CC2 + 255) / 256, 256, 0, stream>>>(agg2, scale2, shift2, skip, out, NN * CC2);

    (void)in_sizes; (void)n_in; (void)out_size; (void)ws_size;
}

// Round 3
// 430.895 us; speedup vs baseline: 2.1281x; 1.3071x over previous
//
#include <hip/hip_runtime.h>
#include <math.h>

// Problem constants (from reference)
constexpr int NN = 50000;
constexpr int EE = 800000;
constexpr int INC = 256, CC1 = 128, CC2 = 64;

typedef short bf16x8 __attribute__((ext_vector_type(8)));
typedef float f32x4 __attribute__((ext_vector_type(4)));

__device__ __forceinline__ unsigned short f2bf(float f) {
    unsigned int u = __builtin_bit_cast(unsigned int, f);
    u = (u + 0x7FFFu + ((u >> 16) & 1u)) >> 16;   // RNE
    return (unsigned short)u;
}
__device__ __forceinline__ float bflo(unsigned int w) {
    return __builtin_bit_cast(float, w << 16);
}
__device__ __forceinline__ float bfhi(unsigned int w) {
    return __builtin_bit_cast(float, w & 0xFFFF0000u);
}

// ---------------- precompute kernels ----------------

__global__ void init_kernel(float* __restrict__ deg, int* __restrict__ count,
                            float* __restrict__ stats, int* __restrict__ cursor, int n) {
    int i = blockIdx.x * 256 + threadIdx.x;
    if (i < 1024) stats[i] = 0.0f;
    if (i == 0) *cursor = 0;
    if (i < n) { deg[i] = 1.0f; count[i] = 0; }
}

__global__ void deg_count_kernel(const int* __restrict__ col, const float* __restrict__ ew,
                                 float* __restrict__ deg, int* __restrict__ count, int e_cnt) {
    int e = blockIdx.x * 256 + threadIdx.x;
    if (e < e_cnt) {
        int c = col[e];
        atomicAdd(&deg[c], ew[e]);
        atomicAdd(&count[c], 1);
    }
}

__global__ void dinv_kernel(float* __restrict__ deg, int n) {
    int i = blockIdx.x * 256 + threadIdx.x;
    if (i < n) deg[i] = rsqrtf(deg[i]);
}

__global__ void alloc_kernel(const int* __restrict__ count, int* __restrict__ start,
                             int* __restrict__ cur, int* __restrict__ cursor, int n) {
    int i = blockIdx.x * 256 + threadIdx.x;
    if (i < n) {
        int s = atomicAdd(cursor, count[i]);
        start[i] = s;
        cur[i] = s;
    }
}

__global__ void fill_kernel(const int* __restrict__ row, const int* __restrict__ col,
                            const float* __restrict__ ew, const float* __restrict__ dinv,
                            int* __restrict__ cur, int* __restrict__ csr_row,
                            float* __restrict__ csr_nrm, int e_cnt) {
    int e = blockIdx.x * 256 + threadIdx.x;
    if (e < e_cnt) {
        int r = row[e], c = col[e];
        float nv = dinv[r] * ew[e] * dinv[c];
        int pos = atomicAdd(&cur[c], 1);
        csr_row[pos] = r;
        csr_nrm[pos] = nv;
    }
}

// ---------------- MFMA GEMM ----------------
// C[n_rows x (N1|N2)] = A[n_rows x K] * [B1|B2][K x (N1+N2)]
// A: fp32 (converted in-register) or bf16. C1 = bf16 out (first N1 cols),
// C2 = fp32 out (next N2 cols, may be absent).
// Per block: 64 rows, 4 waves x 16-row strips. B staged to LDS bf16 [n][k] (pitch K+8).
template<int K, int N1, int N2, bool AF32>
__global__ void __launch_bounds__(256) mfma_gemm(const void* __restrict__ Av,
        const float* __restrict__ B1, const float* __restrict__ B2,
        unsigned short* __restrict__ C1, float* __restrict__ C2, int n_rows) {
    constexpr int NT = N1 + N2;
    constexpr int NG = 64;              // col group staged at a time
    constexpr int KC = K / 8;           // 16B chunks per B row
    constexpr int PITCH = K + 8;        // bf16 elements, breaks bank aliasing
    __shared__ unsigned short Blds[NG * PITCH];

    const int tid = threadIdx.x;
    const int wave = tid >> 6, lane = tid & 63;
    const int quad = lane >> 4, nIdx = lane & 15;
    const int row0 = blockIdx.x * 64 + wave * 16;
    const int arow = row0 + nIdx;
    const int arow_c = (arow < n_rows) ? arow : (n_rows - 1);

    // A fragments for full K held in registers (A[m=lane&15][k=quad*8+j])
    bf16x8 afrag[K / 32];
    if (AF32) {
        const float* A = (const float*)Av;
        const float* ap = A + (long long)arow_c * K + quad * 8;
#pragma unroll
        for (int s = 0; s < K / 32; s++) {
            float4 lo = *(const float4*)(ap + s * 32);
            float4 hi = *(const float4*)(ap + s * 32 + 4);
            bf16x8 f;
            f[0] = (short)f2bf(lo.x); f[1] = (short)f2bf(lo.y);
            f[2] = (short)f2bf(lo.z); f[3] = (short)f2bf(lo.w);
            f[4] = (short)f2bf(hi.x); f[5] = (short)f2bf(hi.y);
            f[6] = (short)f2bf(hi.z); f[7] = (short)f2bf(hi.w);
            afrag[s] = f;
        }
    } else {
        const unsigned short* A = (const unsigned short*)Av;
        const unsigned short* ap = A + (long long)arow_c * K + quad * 8;
#pragma unroll
        for (int s = 0; s < K / 32; s++)
            afrag[s] = *(const bf16x8*)(ap + s * 32);
    }

    for (int g0 = 0; g0 < NT; g0 += NG) {
        if (g0) __syncthreads();
        // stage B cols [g0, g0+NG): thread -> (n = tid&63, kc = tid>>6 step 4)
        {
            int n = tid & 63;
            int col = g0 + n;
            const float* Bp = B1; int Nw = N1; int bcol = col;
            if (N2 > 0 && col >= N1) { Bp = B2; Nw = N2; bcol = col - N1; }
            for (int kc = tid >> 6; kc < KC; kc += 4) {
                int k0 = kc * 8;
                bf16x8 v;
#pragma unroll
                for (int j = 0; j < 8; j++)
                    v[j] = (short)f2bf(Bp[(long long)(k0 + j) * Nw + bcol]);
                *(bf16x8*)(&Blds[n * PITCH + k0]) = v;
            }
        }
        __syncthreads();
        // compute NG/16 col tiles for this wave's 16-row strip
#pragma unroll
        for (int t = 0; t < NG / 16; t++) {
            const unsigned short* bp = &Blds[(t * 16 + nIdx) * PITCH + quad * 8];
            f32x4 acc = {0.0f, 0.0f, 0.0f, 0.0f};
#pragma unroll
            for (int s = 0; s < K / 32; s++) {
                bf16x8 bf = *(const bf16x8*)(bp + s * 32);
                acc = __builtin_amdgcn_mfma_f32_16x16x32_bf16(afrag[s], bf, acc, 0, 0, 0);
            }
            int colBase = g0 + t * 16;
            int ocol = colBase + nIdx;   // C/D: col=lane&15, row=quad*4+reg
#pragma unroll
            for (int r = 0; r < 4; r++) {
                int orow = row0 + quad * 4 + r;
                if (orow < n_rows) {
                    if (N2 == 0 || ocol < N1)
                        C1[(long long)orow * N1 + ocol] = f2bf(acc[r]);
                    else
                        C2[(long long)orow * N2 + (ocol - N1)] = acc[r];
                }
            }
        }
    }
}

// ---------------- gather aggregation (bf16 features, fp32 accum) ----------------
template<int C>
__global__ void gather_agg_bf16(const unsigned short* __restrict__ h, const float* __restrict__ dinv,
                                const float* __restrict__ b, const int* __restrict__ csr_row,
                                const float* __restrict__ csr_nrm, const int* __restrict__ start,
                                const int* __restrict__ count, float* __restrict__ out, int n) {
    constexpr int TPN = C / 8;
    int gid = blockIdx.x * 256 + threadIdx.x;
    int node = gid / TPN;
    int part = gid - node * TPN;
    if (node >= n) return;
    int c8 = part * 8;
    float d = dinv[node];
    float d2 = d * d;
    uint4 hv = *(const uint4*)(h + (long long)node * C + c8);
    float a0 = bflo(hv.x) * d2 + b[c8 + 0];
    float a1 = bfhi(hv.x) * d2 + b[c8 + 1];
    float a2 = bflo(hv.y) * d2 + b[c8 + 2];
    float a3 = bfhi(hv.y) * d2 + b[c8 + 3];
    float a4 = bflo(hv.z) * d2 + b[c8 + 4];
    float a5 = bfhi(hv.z) * d2 + b[c8 + 5];
    float a6 = bflo(hv.w) * d2 + b[c8 + 6];
    float a7 = bfhi(hv.w) * d2 + b[c8 + 7];
    int s = start[node];
    int e = s + count[node];
    for (int j = s; j < e; j++) {
        int nbr = csr_row[j];
        float w = csr_nrm[j];
        uint4 v = *(const uint4*)(h + (long long)nbr * C + c8);
        a0 += bflo(v.x) * w; a1 += bfhi(v.x) * w;
        a2 += bflo(v.y) * w; a3 += bfhi(v.y) * w;
        a4 += bflo(v.z) * w; a5 += bfhi(v.z) * w;
        a6 += bflo(v.w) * w; a7 += bfhi(v.w) * w;
    }
    float4 o0 = {a0, a1, a2, a3}, o1 = {a4, a5, a6, a7};
    *(float4*)(out + (long long)node * C + c8) = o0;
    *(float4*)(out + (long long)node * C + c8 + 4) = o1;
}

// ---------------- batchnorm ----------------

template<int C>
__global__ void bnstats_kernel(const float* __restrict__ x, float* __restrict__ sum,
                               float* __restrict__ sumsq, int n) {
    constexpr int RG = 256 / C;
    constexpr int ROWS = 128;
    const int c = threadIdx.x % C;
    const int rg = threadIdx.x / C;
    const int base = blockIdx.x * ROWS;
    float s = 0.0f, ss = 0.0f;
    for (int r = rg; r < ROWS; r += RG) {
        int nn = base + r;
        if (nn < n) {
            float v = x[(long long)nn * C + c];
            s += v; ss += v * v;
        }
    }
    __shared__ float ls[256], lss[256];
    ls[threadIdx.x] = s; lss[threadIdx.x] = ss;
    __syncthreads();
    if (rg == 0) {
#pragma unroll
        for (int g = 1; g < RG; g++) { s += ls[g * C + c]; ss += lss[g * C + c]; }
        atomicAdd(&sum[c], s);
        atomicAdd(&sumsq[c], ss);
    }
}

__global__ void bnparams_kernel(const float* __restrict__ sum, const float* __restrict__ sumsq,
                                const float* __restrict__ gamma, const float* __restrict__ beta,
                                const float* __restrict__ extra_bias,
                                float* __restrict__ scale, float* __restrict__ shift,
                                int n, int c_cnt) {
    int c = threadIdx.x;
    if (c < c_cnt) {
        float inv_n = 1.0f / (float)n;
        float mu = sum[c] * inv_n;
        float var = sumsq[c] * inv_n - mu * mu;
        if (var < 0.0f) var = 0.0f;
        float sc = gamma[c] * rsqrtf(var + 1e-5f);
        float sh = beta[c] - mu * sc;
        if (extra_bias) sh += extra_bias[c];
        scale[c] = sc; shift[c] = sh;
    }
}

// x1 = gelu(bn(agg1)) stored as bf16 (feeds MFMA gemm2)
template<int C>
__global__ void bn_gelu_kernel(const float* __restrict__ x, const float* __restrict__ scale,
                               const float* __restrict__ shift, unsigned short* __restrict__ out,
                               int total) {
    int i = blockIdx.x * 256 + threadIdx.x;
    if (i >= total) return;
    int c = i % C;
    float v = x[i] * scale[c] + shift[c];
    out[i] = f2bf(v * 0.5f * (1.0f + erff(v * 0.70710678f)));
}

template<int C>
__global__ void final_kernel(const float* __restrict__ x, const float* __restrict__ scale,
                             const float* __restrict__ shift, const float* __restrict__ skip,
                             float* __restrict__ out, int total) {
    int i = blockIdx.x * 256 + threadIdx.x;
    if (i >= total) return;
    int c = i % C;
    out[i] = x[i] * scale[c] + shift[c] + skip[i];
}

// ---------------- launch ----------------

extern "C" void kernel_launch(void* const* d_in, const int* in_sizes, int n_in,
                              void* d_out, int out_size, void* d_ws, size_t ws_size,
                              hipStream_t stream) {
    const float* x   = (const float*)d_in[0];
    const int*   ei  = (const int*)d_in[1];
    const float* ew  = (const float*)d_in[2];
    const float* W1  = (const float*)d_in[3];
    const float* b1  = (const float*)d_in[4];
    const float* W2  = (const float*)d_in[5];
    const float* b2  = (const float*)d_in[6];
    const float* g1  = (const float*)d_in[7];
    const float* be1 = (const float*)d_in[8];
    const float* g2  = (const float*)d_in[9];
    const float* be2 = (const float*)d_in[10];
    const float* Ws  = (const float*)d_in[11];
    const float* bs  = (const float*)d_in[12];
    float* out = (float*)d_out;

    const int* row = ei;            // edge_index[0]
    const int* col = ei + EE;       // edge_index[1]

    // workspace layout
    float* w = (float*)d_ws;
    float* dinv    = w;                                  // N
    float* csr_nrm = dinv + NN;                          // E
    float* agg1    = csr_nrm + EE;                       // N*CC1
    float* agg2    = agg1 + (long long)NN * CC1;         // N*CC2
    float* skip    = agg2 + (long long)NN * CC2;         // N*CC2
    float* stats   = skip + (long long)NN * CC2;         // 1024
    int*   count   = (int*)(stats + 1024);               // N
    int*   startp  = count + NN;                         // N
    int*   curp    = startp + NN;                        // N
    int*   csr_row = curp + NN;                          // E
    int*   cursor  = csr_row + EE;                       // 1 (+3 pad)
    unsigned short* h1b = (unsigned short*)(cursor + 4); // N*CC1
    unsigned short* x1b = h1b + (long long)NN * CC1;     // N*CC1
    unsigned short* h2b = x1b + (long long)NN * CC1;     // N*CC2

    float* sum1   = stats;        // 128
    float* sumsq1 = stats + 128;  // 128
    float* sum2   = stats + 256;  // 64
    float* sumsq2 = stats + 320;  // 64
    float* scale1 = stats + 384;  // 128
    float* shift1 = stats + 512;  // 128
    float* scale2 = stats + 640;  // 64
    float* shift2 = stats + 704;  // 64

    const int nb_N = (NN + 255) / 256;
    const int nb_E = (EE + 255) / 256;
    const int nb_G = (NN + 63) / 64;     // GEMM blocks (64 rows each)

    // CSR + norm precompute
    init_kernel<<<nb_N, 256, 0, stream>>>(dinv, count, stats, cursor, NN);
    deg_count_kernel<<<nb_E, 256, 0, stream>>>(col, ew, dinv, count, EE);
    dinv_kernel<<<nb_N, 256, 0, stream>>>(dinv, NN);
    alloc_kernel<<<nb_N, 256, 0, stream>>>(count, startp, curp, cursor, NN);
    fill_kernel<<<nb_E, 256, 0, stream>>>(row, col, ew, dinv, curp, csr_row, csr_nrm, EE);

    // fused: [h1|skip] = x @ [W1|Ws]  (A fp32 -> bf16 frags in-register)
    mfma_gemm<INC, CC1, CC2, true><<<nb_G, 256, 0, stream>>>(x, W1, Ws, h1b, skip, NN);

    // conv1 aggregation (self loop + b1 fused), fp32 accum
    gather_agg_bf16<CC1><<<(NN * (CC1 / 8) + 255) / 256, 256, 0, stream>>>(
        h1b, dinv, b1, csr_row, csr_nrm, startp, count, agg1, NN);

    // BN1 + GELU -> x1 (bf16)
    bnstats_kernel<CC1><<<(NN + 127) / 128, 256, 0, stream>>>(agg1, sum1, sumsq1, NN);
    bnparams_kernel<<<1, 128, 0, stream>>>(sum1, sumsq1, g1, be1, nullptr, scale1, shift1, NN, CC1);
    bn_gelu_kernel<CC1><<<(NN * CC1 + 255) / 256, 256, 0, stream>>>(agg1, scale1, shift1, x1b, NN * CC1);

    // conv2: h2 = x1 @ W2 (A already bf16)
    mfma_gemm<CC1, CC2, 0, false><<<nb_G, 256, 0, stream>>>(x1b, W2, W2, h2b, nullptr, NN);
    gather_agg_bf16<CC2><<<(NN * (CC2 / 8) + 255) / 256, 256, 0, stream>>>(
        h2b, dinv, b2, csr_row, csr_nrm, startp, count, agg2, NN);

    // BN2 (+bs) + skip -> out
    bnstats_kernel<CC2><<<(NN + 127) / 128, 256, 0, stream>>>(agg2, sum2, sumsq2, NN);
    bnparams_kernel<<<1, 64, 0, stream>>>(sum2, sumsq2, g2, be2, bs, scale2, shift2, NN, CC2);
    final_kernel<CC2><<<(NN * CC2 + 255) / 256, 256, 0, stream>>>(agg2, scale2, shift2, skip, out, NN * CC2);

    (void)in_sizes; (void)n_in; (void)out_size; (void)ws_size;
}

// Round 4
// 334.514 us; speedup vs baseline: 2.7412x; 1.2881x over previous
//
#include <hip/hip_runtime.h>
#include <math.h>

// Problem constants (from reference)
constexpr int NN = 50000;
constexpr int EE = 800000;
constexpr int INC = 256, CC1 = 128, CC2 = 64;

typedef short bf16x8 __attribute__((ext_vector_type(8)));
typedef float f32x4 __attribute__((ext_vector_type(4)));

__device__ __forceinline__ unsigned short f2bf(float f) {
    unsigned int u = __builtin_bit_cast(unsigned int, f);
    u = (u + 0x7FFFu + ((u >> 16) & 1u)) >> 16;   // RNE
    return (unsigned short)u;
}
__device__ __forceinline__ float bflo(unsigned int w) {
    return __builtin_bit_cast(float, w << 16);
}
__device__ __forceinline__ float bfhi(unsigned int w) {
    return __builtin_bit_cast(float, w & 0xFFFF0000u);
}

// ---------------- CSR build (1 atomic per edge) ----------------

__global__ void init_kernel(unsigned long long* __restrict__ packed,
                            float* __restrict__ stats, int* __restrict__ cursor, int n) {
    int i = blockIdx.x * 256 + threadIdx.x;
    if (i < 1024) stats[i] = 0.0f;
    if (i == 0) *cursor = 0;
    if (i < n) packed[i] = 0ULL;
}

// packed[c] += (1<<32) | fix24(ew): hi = incoming count, lo = weighted degree.
// Returned hi word = this edge's rank within its destination segment.
__global__ void rank_kernel(const int* __restrict__ col, const float* __restrict__ ew,
                            unsigned long long* __restrict__ packed, int* __restrict__ rank,
                            int e_cnt) {
    int e = blockIdx.x * 256 + threadIdx.x;
    if (e < e_cnt) {
        int c = col[e];
        unsigned int fx = __float2uint_rn(ew[e] * 16777216.0f);
        unsigned long long old = atomicAdd(&packed[c], (1ULL << 32) | (unsigned long long)fx);
        rank[e] = (int)(old >> 32);
    }
}

// per node: decode count + degree, dinv = rsqrt(deg), allocate CSR segment
__global__ void alloc_kernel(const unsigned long long* __restrict__ packed,
                             float* __restrict__ dinv, int* __restrict__ start,
                             int* __restrict__ count, int* __restrict__ cursor, int n) {
    int i = blockIdx.x * 256 + threadIdx.x;
    if (i < n) {
        unsigned long long p = packed[i];
        int cnt = (int)(p >> 32);
        float deg = 1.0f + (float)(unsigned int)(p & 0xFFFFFFFFu) * (1.0f / 16777216.0f);
        dinv[i] = rsqrtf(deg);
        count[i] = cnt;
        start[i] = atomicAdd(cursor, cnt);
    }
}

// atomic-free fill: pos = start[col] + rank; interleaved (src_row, norm) pairs
__global__ void fill_kernel(const int* __restrict__ row, const int* __restrict__ col,
                            const float* __restrict__ ew, const float* __restrict__ dinv,
                            const int* __restrict__ rank, const int* __restrict__ start,
                            int2* __restrict__ pairs, int e_cnt) {
    int e = blockIdx.x * 256 + threadIdx.x;
    if (e < e_cnt) {
        int r = row[e], c = col[e];
        float nv = dinv[r] * ew[e] * dinv[c];
        int pos = start[c] + rank[e];
        pairs[pos] = make_int2(r, __float_as_int(nv));
    }
}

// ---------------- MFMA GEMM ----------------
// C[n_rows x (N1|N2)] = A[n_rows x K] * [B1|B2][K x (N1+N2)]
// AMODE: 0 = A fp32, 1 = A bf16, 2 = A fp32 with per-k BN scale/shift + exact GELU
// C1 = bf16 out (first N1 cols), C2 = fp32 out (next N2 cols, may be absent).
template<int K, int N1, int N2, int AMODE>
__global__ void __launch_bounds__(256) mfma_gemm(const void* __restrict__ Av,
        const float* __restrict__ B1, const float* __restrict__ B2,
        unsigned short* __restrict__ C1, float* __restrict__ C2,
        const float* __restrict__ scA, const float* __restrict__ shA, int n_rows) {
    constexpr int NT = N1 + N2;
    constexpr int NG = 64;              // col group staged at a time
    constexpr int KC = K / 8;           // 16B chunks per B row
    constexpr int PITCH = K + 8;        // bf16 elements, breaks bank aliasing
    __shared__ unsigned short Blds[NG * PITCH];

    const int tid = threadIdx.x;
    const int wave = tid >> 6, lane = tid & 63;
    const int quad = lane >> 4, nIdx = lane & 15;
    const int row0 = blockIdx.x * 64 + wave * 16;
    const int arow = row0 + nIdx;
    const int arow_c = (arow < n_rows) ? arow : (n_rows - 1);

    // A fragments for full K held in registers (A[m=lane&15][k=quad*8+j+32*s])
    bf16x8 afrag[K / 32];
    if (AMODE == 1) {
        const unsigned short* A = (const unsigned short*)Av;
        const unsigned short* ap = A + (long long)arow_c * K + quad * 8;
#pragma unroll
        for (int s = 0; s < K / 32; s++)
            afrag[s] = *(const bf16x8*)(ap + s * 32);
    } else {
        const float* A = (const float*)Av;
        const float* ap = A + (long long)arow_c * K + quad * 8;
#pragma unroll
        for (int s = 0; s < K / 32; s++) {
            float4 lo = *(const float4*)(ap + s * 32);
            float4 hi = *(const float4*)(ap + s * 32 + 4);
            float v[8] = {lo.x, lo.y, lo.z, lo.w, hi.x, hi.y, hi.z, hi.w};
            if (AMODE == 2) {
                int kb = s * 32 + quad * 8;
                float4 s0 = *(const float4*)(scA + kb);
                float4 s1 = *(const float4*)(scA + kb + 4);
                float4 t0 = *(const float4*)(shA + kb);
                float4 t1 = *(const float4*)(shA + kb + 4);
                float sc[8] = {s0.x, s0.y, s0.z, s0.w, s1.x, s1.y, s1.z, s1.w};
                float sh[8] = {t0.x, t0.y, t0.z, t0.w, t1.x, t1.y, t1.z, t1.w};
#pragma unroll
                for (int j = 0; j < 8; j++) {
                    float u = v[j] * sc[j] + sh[j];
                    v[j] = u * 0.5f * (1.0f + erff(u * 0.70710678f));
                }
            }
            bf16x8 f;
#pragma unroll
            for (int j = 0; j < 8; j++) f[j] = (short)f2bf(v[j]);
            afrag[s] = f;
        }
    }

    for (int g0 = 0; g0 < NT; g0 += NG) {
        if (g0) __syncthreads();
        {
            int n = tid & 63;
            int col = g0 + n;
            const float* Bp = B1; int Nw = N1; int bcol = col;
            if (N2 > 0 && col >= N1) { Bp = B2; Nw = N2; bcol = col - N1; }
            for (int kc = tid >> 6; kc < KC; kc += 4) {
                int k0 = kc * 8;
                bf16x8 v;
#pragma unroll
                for (int j = 0; j < 8; j++)
                    v[j] = (short)f2bf(Bp[(long long)(k0 + j) * Nw + bcol]);
                *(bf16x8*)(&Blds[n * PITCH + k0]) = v;
            }
        }
        __syncthreads();
#pragma unroll
        for (int t = 0; t < NG / 16; t++) {
            const unsigned short* bp = &Blds[(t * 16 + nIdx) * PITCH + quad * 8];
            f32x4 acc = {0.0f, 0.0f, 0.0f, 0.0f};
#pragma unroll
            for (int s = 0; s < K / 32; s++) {
                bf16x8 bf = *(const bf16x8*)(bp + s * 32);
                acc = __builtin_amdgcn_mfma_f32_16x16x32_bf16(afrag[s], bf, acc, 0, 0, 0);
            }
            int ocol = g0 + t * 16 + nIdx;   // C/D: col=lane&15, row=quad*4+reg
#pragma unroll
            for (int r = 0; r < 4; r++) {
                int orow = row0 + quad * 4 + r;
                if (orow < n_rows) {
                    if (N2 == 0 || ocol < N1)
                        C1[(long long)orow * N1 + ocol] = f2bf(acc[r]);
                    else
                        C2[(long long)orow * N2 + (ocol - N1)] = acc[r];
                }
            }
        }
    }
}

// ---------------- gather aggregation (bf16 features, fp32 accum, unroll-4) ----------------
template<int C>
__global__ void gather_agg_bf16(const unsigned short* __restrict__ h, const float* __restrict__ dinv,
                                const float* __restrict__ b, const int2* __restrict__ pairs,
                                const int* __restrict__ start, const int* __restrict__ count,
                                float* __restrict__ out, int n) {
    constexpr int TPN = C / 8;
    int gid = blockIdx.x * 256 + threadIdx.x;
    int node = gid / TPN;
    int part = gid - node * TPN;
    if (node >= n) return;
    int c8 = part * 8;
    float d = dinv[node];
    float d2 = d * d;
    uint4 hv = *(const uint4*)(h + (long long)node * C + c8);
    float a0 = bflo(hv.x) * d2 + b[c8 + 0];
    float a1 = bfhi(hv.x) * d2 + b[c8 + 1];
    float a2 = bflo(hv.y) * d2 + b[c8 + 2];
    float a3 = bfhi(hv.y) * d2 + b[c8 + 3];
    float a4 = bflo(hv.z) * d2 + b[c8 + 4];
    float a5 = bfhi(hv.z) * d2 + b[c8 + 5];
    float a6 = bflo(hv.w) * d2 + b[c8 + 6];
    float a7 = bfhi(hv.w) * d2 + b[c8 + 7];
    const int2* pp = pairs + start[node];
    int m = count[node];
    int j = 0;
    for (; j + 4 <= m; j += 4) {
        int2 p0 = pp[j + 0], p1 = pp[j + 1], p2 = pp[j + 2], p3 = pp[j + 3];
        uint4 v0 = *(const uint4*)(h + (long long)p0.x * C + c8);
        uint4 v1 = *(const uint4*)(h + (long long)p1.x * C + c8);
        uint4 v2 = *(const uint4*)(h + (long long)p2.x * C + c8);
        uint4 v3 = *(const uint4*)(h + (long long)p3.x * C + c8);
        float w0 = __int_as_float(p0.y), w1 = __int_as_float(p1.y);
        float w2 = __int_as_float(p2.y), w3 = __int_as_float(p3.y);
        a0 += bflo(v0.x) * w0; a1 += bfhi(v0.x) * w0;
        a2 += bflo(v0.y) * w0; a3 += bfhi(v0.y) * w0;
        a4 += bflo(v0.z) * w0; a5 += bfhi(v0.z) * w0;
        a6 += bflo(v0.w) * w0; a7 += bfhi(v0.w) * w0;
        a0 += bflo(v1.x) * w1; a1 += bfhi(v1.x) * w1;
        a2 += bflo(v1.y) * w1; a3 += bfhi(v1.y) * w1;
        a4 += bflo(v1.z) * w1; a5 += bfhi(v1.z) * w1;
        a6 += bflo(v1.w) * w1; a7 += bfhi(v1.w) * w1;
        a0 += bflo(v2.x) * w2; a1 += bfhi(v2.x) * w2;
        a2 += bflo(v2.y) * w2; a3 += bfhi(v2.y) * w2;
        a4 += bflo(v2.z) * w2; a5 += bfhi(v2.z) * w2;
        a6 += bflo(v2.w) * w2; a7 += bfhi(v2.w) * w2;
        a0 += bflo(v3.x) * w3; a1 += bfhi(v3.x) * w3;
        a2 += bflo(v3.y) * w3; a3 += bfhi(v3.y) * w3;
        a4 += bflo(v3.z) * w3; a5 += bfhi(v3.z) * w3;
        a6 += bflo(v3.w) * w3; a7 += bfhi(v3.w) * w3;
    }
    for (; j < m; j++) {
        int2 p = pp[j];
        float w = __int_as_float(p.y);
        uint4 v = *(const uint4*)(h + (long long)p.x * C + c8);
        a0 += bflo(v.x) * w; a1 += bfhi(v.x) * w;
        a2 += bflo(v.y) * w; a3 += bfhi(v.y) * w;
        a4 += bflo(v.z) * w; a5 += bfhi(v.z) * w;
        a6 += bflo(v.w) * w; a7 += bfhi(v.w) * w;
    }
    float4 o0 = {a0, a1, a2, a3}, o1 = {a4, a5, a6, a7};
    *(float4*)(out + (long long)node * C + c8) = o0;
    *(float4*)(out + (long long)node * C + c8 + 4) = o1;
}

// ---------------- batchnorm ----------------

template<int C>
__global__ void bnstats_kernel(const float* __restrict__ x, float* __restrict__ sum,
                               float* __restrict__ sumsq, int n) {
    constexpr int RG = 256 / C;
    constexpr int ROWS = 128;
    const int c = threadIdx.x % C;
    const int rg = threadIdx.x / C;
    const int base = blockIdx.x * ROWS;
    float s = 0.0f, ss = 0.0f;
    for (int r = rg; r < ROWS; r += RG) {
        int nn = base + r;
        if (nn < n) {
            float v = x[(long long)nn * C + c];
            s += v; ss += v * v;
        }
    }
    __shared__ float ls[256], lss[256];
    ls[threadIdx.x] = s; lss[threadIdx.x] = ss;
    __syncthreads();
    if (rg == 0) {
#pragma unroll
        for (int g = 1; g < RG; g++) { s += ls[g * C + c]; ss += lss[g * C + c]; }
        atomicAdd(&sum[c], s);
        atomicAdd(&sumsq[c], ss);
    }
}

__global__ void bnparams_kernel(const float* __restrict__ sum, const float* __restrict__ sumsq,
                                const float* __restrict__ gamma, const float* __restrict__ beta,
                                const float* __restrict__ extra_bias,
                                float* __restrict__ scale, float* __restrict__ shift,
                                int n, int c_cnt) {
    int c = threadIdx.x;
    if (c < c_cnt) {
        float inv_n = 1.0f / (float)n;
        float mu = sum[c] * inv_n;
        float var = sumsq[c] * inv_n - mu * mu;
        if (var < 0.0f) var = 0.0f;
        float sc = gamma[c] * rsqrtf(var + 1e-5f);
        float sh = beta[c] - mu * sc;
        if (extra_bias) sh += extra_bias[c];
        scale[c] = sc; shift[c] = sh;
    }
}

template<int C>
__global__ void final_kernel(const float* __restrict__ x, const float* __restrict__ scale,
                             const float* __restrict__ shift, const float* __restrict__ skip,
                             float* __restrict__ out, int total) {
    int i = blockIdx.x * 256 + threadIdx.x;
    if (i >= total) return;
    int c = i % C;
    out[i] = x[i] * scale[c] + shift[c] + skip[i];
}

// ---------------- launch ----------------

extern "C" void kernel_launch(void* const* d_in, const int* in_sizes, int n_in,
                              void* d_out, int out_size, void* d_ws, size_t ws_size,
                              hipStream_t stream) {
    const float* x   = (const float*)d_in[0];
    const int*   ei  = (const int*)d_in[1];
    const float* ew  = (const float*)d_in[2];
    const float* W1  = (const float*)d_in[3];
    const float* b1  = (const float*)d_in[4];
    const float* W2  = (const float*)d_in[5];
    const float* b2  = (const float*)d_in[6];
    const float* g1  = (const float*)d_in[7];
    const float* be1 = (const float*)d_in[8];
    const float* g2  = (const float*)d_in[9];
    const float* be2 = (const float*)d_in[10];
    const float* Ws  = (const float*)d_in[11];
    const float* bs  = (const float*)d_in[12];
    float* out = (float*)d_out;

    const int* row = ei;            // edge_index[0]
    const int* col = ei + EE;       // edge_index[1]

    // workspace layout (all segment offsets multiples of 16 B)
    float* w = (float*)d_ws;
    float* dinv    = w;                                   // N
    float* agg1    = dinv + NN;                           // N*CC1
    float* agg2    = agg1 + (long long)NN * CC1;          // N*CC2
    float* skip    = agg2 + (long long)NN * CC2;          // N*CC2
    float* stats   = skip + (long long)NN * CC2;          // 1024
    unsigned long long* packed = (unsigned long long*)(stats + 1024);  // N
    int*   rank    = (int*)(packed + NN);                 // E
    int*   startp  = rank + EE;                           // N
    int*   countp  = startp + NN;                         // N
    int*   cursor  = countp + NN;                         // 1 (+3 pad)
    int2*  pairs   = (int2*)(cursor + 4);                 // E
    unsigned short* h1b = (unsigned short*)(pairs + EE);  // N*CC1
    unsigned short* h2b = h1b + (long long)NN * CC1;      // N*CC2

    float* sum1   = stats;        // 128
    float* sumsq1 = stats + 128;  // 128
    float* sum2   = stats + 256;  // 64
    float* sumsq2 = stats + 320;  // 64
    float* scale1 = stats + 384;  // 128
    float* shift1 = stats + 512;  // 128
    float* scale2 = stats + 640;  // 64
    float* shift2 = stats + 704;  // 64

    const int nb_N = (NN + 255) / 256;
    const int nb_E = (EE + 255) / 256;
    const int nb_G = (NN + 63) / 64;     // GEMM blocks (64 rows each)

    // CSR + degree precompute: 1 packed atomic per edge
    init_kernel<<<nb_N, 256, 0, stream>>>(packed, stats, cursor, NN);
    rank_kernel<<<nb_E, 256, 0, stream>>>(col, ew, packed, rank, EE);
    alloc_kernel<<<nb_N, 256, 0, stream>>>(packed, dinv, startp, countp, cursor, NN);
    fill_kernel<<<nb_E, 256, 0, stream>>>(row, col, ew, dinv, rank, startp, pairs, EE);

    // fused: [h1|skip] = x @ [W1|Ws]
    mfma_gemm<INC, CC1, CC2, 0><<<nb_G, 256, 0, stream>>>(x, W1, Ws, h1b, skip,
                                                          nullptr, nullptr, NN);
    // conv1 aggregation (self loop + b1 fused)
    gather_agg_bf16<CC1><<<(NN * (CC1 / 8) + 255) / 256, 256, 0, stream>>>(
        h1b, dinv, b1, pairs, startp, countp, agg1, NN);

    // BN1 stats; BN1+GELU applied inside gemm2's A-load
    bnstats_kernel<CC1><<<(NN + 127) / 128, 256, 0, stream>>>(agg1, sum1, sumsq1, NN);
    bnparams_kernel<<<1, 128, 0, stream>>>(sum1, sumsq1, g1, be1, nullptr, scale1, shift1, NN, CC1);

    // conv2: h2 = gelu(bn(agg1)) @ W2, fused epilogue-on-A
    mfma_gemm<CC1, CC2, 0, 2><<<nb_G, 256, 0, stream>>>(agg1, W2, W2, h2b, nullptr,
                                                        scale1, shift1, NN);
    gather_agg_bf16<CC2><<<(NN * (CC2 / 8) + 255) / 256, 256, 0, stream>>>(
        h2b, dinv, b2, pairs, startp, countp, agg2, NN);

    // BN2 (+bs) + skip -> out
    bnstats_kernel<CC2><<<(NN + 127) / 128, 256, 0, stream>>>(agg2, sum2, sumsq2, NN);
    bnparams_kernel<<<1, 64, 0, stream>>>(sum2, sumsq2, g2, be2, bs, scale2, shift2, NN, CC2);
    final_kernel<CC2><<<(NN * CC2 + 255) / 256, 256, 0, stream>>>(agg2, scale2, shift2, skip, out, NN * CC2);

    (void)in_sizes; (void)n_in; (void)out_size; (void)ws_size;
}

// Round 5
// 317.595 us; speedup vs baseline: 2.8873x; 1.0533x over previous
//
#include <hip/hip_runtime.h>
#include <math.h>

// Problem constants (from reference)
constexpr int NN = 50000;
constexpr int EE = 800000;
constexpr int INC = 256, CC1 = 128, CC2 = 64;

typedef short bf16x8 __attribute__((ext_vector_type(8)));
typedef float f32x4 __attribute__((ext_vector_type(4)));

__device__ __forceinline__ unsigned short f2bf(float f) {
    unsigned int u = __builtin_bit_cast(unsigned int, f);
    u = (u + 0x7FFFu + ((u >> 16) & 1u)) >> 16;   // RNE
    return (unsigned short)u;
}
__device__ __forceinline__ float bf2f(unsigned short u) {
    return __builtin_bit_cast(float, (unsigned int)u << 16);
}
__device__ __forceinline__ float bflo(unsigned int w) {
    return __builtin_bit_cast(float, w << 16);
}
__device__ __forceinline__ float bfhi(unsigned int w) {
    return __builtin_bit_cast(float, w & 0xFFFF0000u);
}
__device__ __forceinline__ unsigned int packbf2(float lo, float hi) {
    return (unsigned int)f2bf(lo) | ((unsigned int)f2bf(hi) << 16);
}

// ---------------- hybrid: gemm1 ([h1|skip] = x @ [W1|Ws]) + rank atomics ----------------
// Blocks [0, gemm_blocks): MFMA GEMM, fp32 A -> bf16 frags, dual bf16 outputs.
// Blocks [gemm_blocks, ...): 1 packed 64-bit atomic per edge (count<<32 | fix24(ew)),
// returned hi word = edge's rank within its destination segment. Independent work;
// atomic pipe and MFMA pipe co-schedule (m114), so the GEMM hides under the atomics.
__global__ void __launch_bounds__(256) gemm1_rank_kernel(
        const float* __restrict__ A, const float* __restrict__ B1, const float* __restrict__ B2,
        unsigned short* __restrict__ C1, unsigned short* __restrict__ C2,
        const int* __restrict__ col, const float* __restrict__ ew,
        unsigned long long* __restrict__ packed, int* __restrict__ rank, int gemm_blocks) {
    constexpr int K = INC, N1 = CC1, N2 = CC2, NT = N1 + N2;
    constexpr int NG = 64, KC = K / 8, PITCH = K + 8;
    __shared__ unsigned short Blds[NG * PITCH];

    if ((int)blockIdx.x >= gemm_blocks) {
        int e = (blockIdx.x - gemm_blocks) * 256 + threadIdx.x;
        if (e < EE) {
            int c = col[e];
            unsigned int fx = __float2uint_rn(ew[e] * 16777216.0f);
            unsigned long long old =
                atomicAdd(&packed[c], (1ULL << 32) | (unsigned long long)fx);
            rank[e] = (int)(old >> 32);
        }
        return;
    }

    const int tid = threadIdx.x;
    const int wave = tid >> 6, lane = tid & 63;
    const int quad = lane >> 4, nIdx = lane & 15;
    const int row0 = blockIdx.x * 64 + wave * 16;
    const int arow = row0 + nIdx;
    const int arow_c = (arow < NN) ? arow : (NN - 1);

    bf16x8 afrag[K / 32];
    {
        const float* ap = A + (long long)arow_c * K + quad * 8;
#pragma unroll
        for (int s = 0; s < K / 32; s++) {
            float4 lo = *(const float4*)(ap + s * 32);
            float4 hi = *(const float4*)(ap + s * 32 + 4);
            bf16x8 f;
            f[0] = (short)f2bf(lo.x); f[1] = (short)f2bf(lo.y);
            f[2] = (short)f2bf(lo.z); f[3] = (short)f2bf(lo.w);
            f[4] = (short)f2bf(hi.x); f[5] = (short)f2bf(hi.y);
            f[6] = (short)f2bf(hi.z); f[7] = (short)f2bf(hi.w);
            afrag[s] = f;
        }
    }

    for (int g0 = 0; g0 < NT; g0 += NG) {
        if (g0) __syncthreads();
        {
            int n = tid & 63;
            int gcol = g0 + n;
            const float* Bp = B1; int Nw = N1; int bcol = gcol;
            if (gcol >= N1) { Bp = B2; Nw = N2; bcol = gcol - N1; }
            for (int kc = tid >> 6; kc < KC; kc += 4) {
                int k0 = kc * 8;
                bf16x8 v;
#pragma unroll
                for (int j = 0; j < 8; j++)
                    v[j] = (short)f2bf(Bp[(long long)(k0 + j) * Nw + bcol]);
                *(bf16x8*)(&Blds[n * PITCH + k0]) = v;
            }
        }
        __syncthreads();
#pragma unroll
        for (int t = 0; t < NG / 16; t++) {
            const unsigned short* bp = &Blds[(t * 16 + nIdx) * PITCH + quad * 8];
            f32x4 acc = {0.0f, 0.0f, 0.0f, 0.0f};
#pragma unroll
            for (int s = 0; s < K / 32; s++) {
                bf16x8 bf = *(const bf16x8*)(bp + s * 32);
                acc = __builtin_amdgcn_mfma_f32_16x16x32_bf16(afrag[s], bf, acc, 0, 0, 0);
            }
            int ocol = g0 + t * 16 + nIdx;   // C/D: col=lane&15, row=quad*4+reg
#pragma unroll
            for (int r = 0; r < 4; r++) {
                int orow = row0 + quad * 4 + r;
                if (orow < NN) {
                    if (ocol < N1)
                        C1[(long long)orow * N1 + ocol] = f2bf(acc[r]);
                    else
                        C2[(long long)orow * N2 + (ocol - N1)] = f2bf(acc[r]);
                }
            }
        }
    }
}

// ---------------- CSR alloc / fill ----------------

__global__ void alloc_kernel(const unsigned long long* __restrict__ packed,
                             float* __restrict__ dinv, int* __restrict__ start,
                             int* __restrict__ count, int* __restrict__ cursor, int n) {
    int i = blockIdx.x * 256 + threadIdx.x;
    if (i < n) {
        unsigned long long p = packed[i];
        int cnt = (int)(p >> 32);
        float deg = 1.0f + (float)(unsigned int)(p & 0xFFFFFFFFu) * (1.0f / 16777216.0f);
        dinv[i] = rsqrtf(deg);
        count[i] = cnt;
        start[i] = atomicAdd(cursor, cnt);
    }
}

__global__ void fill_kernel(const int* __restrict__ row, const int* __restrict__ col,
                            const float* __restrict__ ew, const float* __restrict__ dinv,
                            const int* __restrict__ rank, const int* __restrict__ start,
                            int2* __restrict__ pairs, int e_cnt) {
    int e = blockIdx.x * 256 + threadIdx.x;
    if (e < e_cnt) {
        int r = row[e], c = col[e];
        float nv = dinv[r] * ew[e] * dinv[c];
        int pos = start[c] + rank[e];
        pairs[pos] = make_int2(r, __float_as_int(nv));
    }
}

// ---------------- gemm2: h2 = gelu(bn(agg1)) @ W2, bf16 A, BN params in-block ----------------
__global__ void __launch_bounds__(256) gemm2_kernel(
        const unsigned short* __restrict__ A, const float* __restrict__ B,
        unsigned short* __restrict__ C,
        const float* __restrict__ sum, const float* __restrict__ sumsq,
        const float* __restrict__ gamma, const float* __restrict__ beta, int n_rows) {
    constexpr int K = CC1, N = CC2;
    constexpr int KC = K / 8, PITCH = K + 8;
    __shared__ unsigned short Blds[N * PITCH];
    __shared__ float scL[K], shL[K];

    const int tid = threadIdx.x;
    if (tid < K) {
        float inv_n = 1.0f / (float)n_rows;
        float mu = sum[tid] * inv_n;
        float var = fmaxf(sumsq[tid] * inv_n - mu * mu, 0.0f);
        float sc = gamma[tid] * rsqrtf(var + 1e-5f);
        scL[tid] = sc; shL[tid] = beta[tid] - mu * sc;
    }
    // stage B (W2, K x N) as bf16 [n][k]
    {
        int n = tid & 63;
        for (int kc = tid >> 6; kc < KC; kc += 4) {
            int k0 = kc * 8;
            bf16x8 v;
#pragma unroll
            for (int j = 0; j < 8; j++)
                v[j] = (short)f2bf(B[(long long)(k0 + j) * N + n]);
            *(bf16x8*)(&Blds[n * PITCH + k0]) = v;
        }
    }
    __syncthreads();

    const int wave = tid >> 6, lane = tid & 63;
    const int quad = lane >> 4, nIdx = lane & 15;
    const int row0 = blockIdx.x * 64 + wave * 16;
    const int arow = row0 + nIdx;
    const int arow_c = (arow < n_rows) ? arow : (n_rows - 1);

    bf16x8 afrag[K / 32];
    {
        const unsigned short* ap = A + (long long)arow_c * K + quad * 8;
#pragma unroll
        for (int s = 0; s < K / 32; s++) {
            bf16x8 raw = *(const bf16x8*)(ap + s * 32);
            int kb = s * 32 + quad * 8;
            bf16x8 f;
#pragma unroll
            for (int j = 0; j < 8; j++) {
                float u = bf2f((unsigned short)raw[j]) * scL[kb + j] + shL[kb + j];
                float v = u * 0.5f * (1.0f + erff(u * 0.70710678f));
                f[j] = (short)f2bf(v);
            }
            afrag[s] = f;
        }
    }
#pragma unroll
    for (int t = 0; t < N / 16; t++) {
        const unsigned short* bp = &Blds[(t * 16 + nIdx) * PITCH + quad * 8];
        f32x4 acc = {0.0f, 0.0f, 0.0f, 0.0f};
#pragma unroll
        for (int s = 0; s < K / 32; s++) {
            bf16x8 bf = *(const bf16x8*)(bp + s * 32);
            acc = __builtin_amdgcn_mfma_f32_16x16x32_bf16(afrag[s], bf, acc, 0, 0, 0);
        }
        int ocol = t * 16 + nIdx;
#pragma unroll
        for (int r = 0; r < 4; r++) {
            int orow = row0 + quad * 4 + r;
            if (orow < n_rows)
                C[(long long)orow * N + ocol] = f2bf(acc[r]);
        }
    }
}

// ---------------- gather aggregation (bf16 in/out, fp32 accum, unroll-8) ----------------
template<int C>
__global__ void gather_agg(const unsigned short* __restrict__ h, const float* __restrict__ dinv,
                           const float* __restrict__ b, const int2* __restrict__ pairs,
                           const int* __restrict__ start, const int* __restrict__ count,
                           unsigned short* __restrict__ outb, int n) {
    constexpr int TPN = C / 8;
    int gid = blockIdx.x * 256 + threadIdx.x;
    int node = gid / TPN;
    int part = gid - node * TPN;
    if (node >= n) return;
    int c8 = part * 8;
    float d = dinv[node];
    float d2 = d * d;
    uint4 hv = *(const uint4*)(h + (long long)node * C + c8);
    float a0 = bflo(hv.x) * d2 + b[c8 + 0];
    float a1 = bfhi(hv.x) * d2 + b[c8 + 1];
    float a2 = bflo(hv.y) * d2 + b[c8 + 2];
    float a3 = bfhi(hv.y) * d2 + b[c8 + 3];
    float a4 = bflo(hv.z) * d2 + b[c8 + 4];
    float a5 = bfhi(hv.z) * d2 + b[c8 + 5];
    float a6 = bflo(hv.w) * d2 + b[c8 + 6];
    float a7 = bfhi(hv.w) * d2 + b[c8 + 7];
    const int2* pp = pairs + start[node];
    int m = count[node];
    int j = 0;
    for (; j + 8 <= m; j += 8) {
        int2 p[8];
#pragma unroll
        for (int i = 0; i < 8; i++) p[i] = pp[j + i];
        uint4 v[8];
#pragma unroll
        for (int i = 0; i < 8; i++)
            v[i] = *(const uint4*)(h + (long long)p[i].x * C + c8);
#pragma unroll
        for (int i = 0; i < 8; i++) {
            float w = __int_as_float(p[i].y);
            a0 += bflo(v[i].x) * w; a1 += bfhi(v[i].x) * w;
            a2 += bflo(v[i].y) * w; a3 += bfhi(v[i].y) * w;
            a4 += bflo(v[i].z) * w; a5 += bfhi(v[i].z) * w;
            a6 += bflo(v[i].w) * w; a7 += bfhi(v[i].w) * w;
        }
    }
    for (; j < m; j++) {
        int2 p = pp[j];
        float w = __int_as_float(p.y);
        uint4 v = *(const uint4*)(h + (long long)p.x * C + c8);
        a0 += bflo(v.x) * w; a1 += bfhi(v.x) * w;
        a2 += bflo(v.y) * w; a3 += bfhi(v.y) * w;
        a4 += bflo(v.z) * w; a5 += bfhi(v.z) * w;
        a6 += bflo(v.w) * w; a7 += bfhi(v.w) * w;
    }
    uint4 o;
    o.x = packbf2(a0, a1); o.y = packbf2(a2, a3);
    o.z = packbf2(a4, a5); o.w = packbf2(a6, a7);
    *(uint4*)(outb + (long long)node * C + c8) = o;
}

// ---------------- batchnorm stats over bf16 ----------------
template<int C>
__global__ void bnstats_bf16(const unsigned short* __restrict__ x, float* __restrict__ sum,
                             float* __restrict__ sumsq, int n) {
    constexpr int PR = C / 2;       // uints per row
    constexpr int RG = 256 / PR;    // rows in flight
    constexpr int ROWS = 256;
    const int cp = threadIdx.x % PR;
    const int rg = threadIdx.x / PR;
    const int base = blockIdx.x * ROWS;
    const unsigned int* xu = (const unsigned int*)x;
    float s0 = 0, ss0 = 0, s1 = 0, ss1 = 0;
    for (int r = rg; r < ROWS; r += RG) {
        int nn = base + r;
        if (nn < n) {
            unsigned int v = xu[(long long)nn * PR + cp];
            float lo = bflo(v), hi = bfhi(v);
            s0 += lo; ss0 += lo * lo; s1 += hi; ss1 += hi * hi;
        }
    }
    __shared__ float red[4][256];
    red[0][threadIdx.x] = s0; red[1][threadIdx.x] = ss0;
    red[2][threadIdx.x] = s1; red[3][threadIdx.x] = ss1;
    __syncthreads();
    if (rg == 0) {
#pragma unroll
        for (int g = 1; g < RG; g++) {
            s0 += red[0][g * PR + cp]; ss0 += red[1][g * PR + cp];
            s1 += red[2][g * PR + cp]; ss1 += red[3][g * PR + cp];
        }
        atomicAdd(&sum[2 * cp], s0);     atomicAdd(&sumsq[2 * cp], ss0);
        atomicAdd(&sum[2 * cp + 1], s1); atomicAdd(&sumsq[2 * cp + 1], ss1);
    }
}

// ---------------- final: out = bn2(agg2) + bs + skip (params in-block) ----------------
__global__ void final_kernel(const unsigned short* __restrict__ agg2b,
                             const unsigned short* __restrict__ skipb,
                             const float* __restrict__ sum, const float* __restrict__ sumsq,
                             const float* __restrict__ gamma, const float* __restrict__ beta,
                             const float* __restrict__ bs, float* __restrict__ out, int n) {
    __shared__ float sc[CC2], sh[CC2];
    if (threadIdx.x < CC2) {
        float inv_n = 1.0f / (float)n;
        float mu = sum[threadIdx.x] * inv_n;
        float var = fmaxf(sumsq[threadIdx.x] * inv_n - mu * mu, 0.0f);
        float s = gamma[threadIdx.x] * rsqrtf(var + 1e-5f);
        sc[threadIdx.x] = s;
        sh[threadIdx.x] = beta[threadIdx.x] - mu * s + bs[threadIdx.x];
    }
    __syncthreads();
    int i2 = blockIdx.x * 256 + threadIdx.x;         // over n * C/2
    if (i2 >= n * (CC2 / 2)) return;
    unsigned int av = ((const unsigned int*)agg2b)[i2];
    unsigned int sv = ((const unsigned int*)skipb)[i2];
    int c2 = (i2 % (CC2 / 2)) * 2;
    float2 o;
    o.x = bflo(av) * sc[c2] + sh[c2] + bflo(sv);
    o.y = bfhi(av) * sc[c2 + 1] + sh[c2 + 1] + bfhi(sv);
    *(float2*)(out + 2 * (long long)i2) = o;
}

// ---------------- launch ----------------

extern "C" void kernel_launch(void* const* d_in, const int* in_sizes, int n_in,
                              void* d_out, int out_size, void* d_ws, size_t ws_size,
                              hipStream_t stream) {
    const float* x   = (const float*)d_in[0];
    const int*   ei  = (const int*)d_in[1];
    const float* ew  = (const float*)d_in[2];
    const float* W1  = (const float*)d_in[3];
    const float* b1  = (const float*)d_in[4];
    const float* W2  = (const float*)d_in[5];
    const float* b2  = (const float*)d_in[6];
    const float* g1  = (const float*)d_in[7];
    const float* be1 = (const float*)d_in[8];
    const float* g2  = (const float*)d_in[9];
    const float* be2 = (const float*)d_in[10];
    const float* Ws  = (const float*)d_in[11];
    const float* bs  = (const float*)d_in[12];
    float* out = (float*)d_out;

    const int* row = ei;            // edge_index[0]
    const int* col = ei + EE;       // edge_index[1]

    // workspace layout
    char* wp = (char*)d_ws;
    float* stats = (float*)wp;                                   // 1024 floats
    float* sum1   = stats;        // 128
    float* sumsq1 = stats + 128;  // 128
    float* sum2   = stats + 256;  // 64
    float* sumsq2 = stats + 320;  // 64
    int*   cursor = (int*)(wp + 4096);                           // 16 B
    unsigned long long* packed = (unsigned long long*)(wp + 4112); // N*8
    char* p2 = wp + 4112 + (size_t)NN * 8;                       // 16-aligned
    int*   rank   = (int*)p2;             p2 += (size_t)EE * 4;
    int*   startp = (int*)p2;             p2 += (size_t)NN * 4;
    int*   countp = (int*)p2;             p2 += (size_t)NN * 4;
    float* dinv   = (float*)p2;           p2 += (size_t)NN * 4;
    int2*  pairs  = (int2*)p2;            p2 += (size_t)EE * 8;
    unsigned short* h1b   = (unsigned short*)p2; p2 += (size_t)NN * CC1 * 2;
    unsigned short* h2b   = (unsigned short*)p2; p2 += (size_t)NN * CC2 * 2;
    unsigned short* agg1b = (unsigned short*)p2; p2 += (size_t)NN * CC1 * 2;
    unsigned short* agg2b = (unsigned short*)p2; p2 += (size_t)NN * CC2 * 2;
    unsigned short* skipb = (unsigned short*)p2; p2 += (size_t)NN * CC2 * 2;

    const int nb_N = (NN + 255) / 256;
    const int nb_E = (EE + 255) / 256;
    const int nb_G = (NN + 63) / 64;     // 64-row GEMM blocks

    // zero stats + cursor + packed in one memset
    hipMemsetAsync(wp, 0, 4112 + (size_t)NN * 8, stream);

    // hybrid: gemm1 (MFMA) + rank (atomics) co-scheduled
    gemm1_rank_kernel<<<nb_G + nb_E, 256, 0, stream>>>(
        x, W1, Ws, h1b, skipb, col, ew, packed, rank, nb_G);

    alloc_kernel<<<nb_N, 256, 0, stream>>>(packed, dinv, startp, countp, cursor, NN);
    fill_kernel<<<nb_E, 256, 0, stream>>>(row, col, ew, dinv, rank, startp, pairs, EE);

    // conv1 aggregation (self loop + b1 fused) -> bf16
    gather_agg<CC1><<<(NN * (CC1 / 8) + 255) / 256, 256, 0, stream>>>(
        h1b, dinv, b1, pairs, startp, countp, agg1b, NN);
    bnstats_bf16<CC1><<<(NN + 255) / 256, 256, 0, stream>>>(agg1b, sum1, sumsq1, NN);

    // conv2: h2 = gelu(bn1(agg1)) @ W2 (BN params computed in-block)
    gemm2_kernel<<<nb_G, 256, 0, stream>>>(agg1b, W2, h2b, sum1, sumsq1, g1, be1, NN);
    gather_agg<CC2><<<(NN * (CC2 / 8) + 255) / 256, 256, 0, stream>>>(
        h2b, dinv, b2, pairs, startp, countp, agg2b, NN);
    bnstats_bf16<CC2><<<(NN + 255) / 256, 256, 0, stream>>>(agg2b, sum2, sumsq2, NN);

    // out = bn2(agg2) + bs + skip
    final_kernel<<<(NN * (CC2 / 2) + 255) / 256, 256, 0, stream>>>(
        agg2b, skipb, sum2, sumsq2, g2, be2, bs, out, NN);

    (void)in_sizes; (void)n_in; (void)out_size; (void)ws_size;
}